// Round 4
// baseline (270.862 us; speedup 1.0000x reference)
//
#include <hip/hip_runtime.h>

// ---------------------------------------------------------------------------
// RefineIUGraphLayer: D=256, H=16, HD=16, N=16384, B=64, S=128, M=8192
//   1) qkv  = seq_feat @ in_proj_w^T + b       (bf16 MFMA gemm, bf16 out)
//   2) attn = MHA(qkv)                         (f32 per-thread, bf16 in/out)
//   3) seq  = attn @ out_proj_w^T + b          (gemm, writes seq + seq^T)
//   4) agg-partials = p1norm-attn(user, seq)   (fused, DMA-dbuf, j-split x2)
//   5) out  = user + combine(agg) @ trans_w^T + b   (fused final gemm)
// ---------------------------------------------------------------------------

typedef __bf16 bf16_t;
typedef __bf16 bf16x8 __attribute__((ext_vector_type(8)));
typedef __bf16 bf16x4 __attribute__((ext_vector_type(4)));
typedef float  f32x4  __attribute__((ext_vector_type(4)));
typedef unsigned int u32x4 __attribute__((ext_vector_type(4)));

#define MFMA16(a, b, c) __builtin_amdgcn_mfma_f32_16x16x32_bf16((a), (b), (c), 0, 0, 0)

#define AS1 __attribute__((address_space(1)))
#define AS3 __attribute__((address_space(3)))
// 16B direct global->LDS DMA. LDS dest = wave-uniform base + lane*16;
// per-lane global source address carries the swizzle.
#define GLOAD_LDS16(g, l) \
    __builtin_amdgcn_global_load_lds((const AS1 unsigned int*)(const void*)(g), \
                                     (AS3 unsigned int*)(void*)(l), 16, 0, 0)

// 3-bit chunk XOR swizzles (involution; applied on write-source addr & read).
__device__ __forceinline__ int swz256(int row, int k) { return row * 256 + (k ^ ((row & 7) << 3)); }
__device__ __forceinline__ int swz64 (int row, int k) { return row * 64  + (k ^ ((row & 7) << 3)); }
// P-tile byte swizzle: balanced for b16 writes AND b128 reads.
__device__ __forceinline__ int pswz(int row) { return ((row & 3) << 4) ^ (((row >> 2) & 3) << 5); }

// --------------------------- f32 -> bf16 convert ---------------------------
__global__ void k_cvt(const float* __restrict__ s, bf16_t* __restrict__ d, int n4) {
    int i  = blockIdx.x * blockDim.x + threadIdx.x;
    int st = gridDim.x * blockDim.x;
    for (; i < n4; i += st) {
        float4 v = ((const float4*)s)[i];
        bf16x4 o = { (bf16_t)v.x, (bf16_t)v.y, (bf16_t)v.z, (bf16_t)v.w };
        ((bf16x4*)d)[i] = o;
    }
}

// --------------- generic C = A @ B^T + bias, bf16 out ----------------------
__global__ __launch_bounds__(256, 1)
void k_gemm_bt(const bf16_t* __restrict__ A, const bf16_t* __restrict__ B,
               const float* __restrict__ bias, bf16_t* __restrict__ Cb, int N) {
    __shared__ bf16_t Al[64 * 256];
    __shared__ bf16_t Bl[64 * 256];
    const int tid  = threadIdx.x;
    const int lane = tid & 63;
    const int w    = tid >> 6;
    const int l15  = lane & 15;
    const int l4   = lane >> 4;
    const int rb = blockIdx.y * 64, cb = blockIdx.x * 64;

    {
        const u32x4* sa = (const u32x4*)(A + (size_t)rb * 256);
        const u32x4* sb = (const u32x4*)(B + (size_t)cb * 256);
        u32x4* da = (u32x4*)Al;
        u32x4* db = (u32x4*)Bl;
#pragma unroll
        for (int i = 0; i < 8; ++i) {
            int ch  = i * 256 + tid;
            int row = ch >> 5, cp = ch & 31;
            int sch = (ch & ~31) | (cp ^ (row & 7));
            da[sch] = sa[ch];
            db[sch] = sb[ch];
        }
    }
    __syncthreads();

    f32x4 acc[4];
#pragma unroll
    for (int n = 0; n < 4; ++n) acc[n] = (f32x4){0.f, 0.f, 0.f, 0.f};

#pragma unroll
    for (int t = 0; t < 8; ++t) {
        int k = t * 32 + l4 * 8;
        bf16x8 af = *(const bf16x8*)(Al + swz256(16 * w + l15, k));
#pragma unroll
        for (int n = 0; n < 4; ++n) {
            bf16x8 bfr = *(const bf16x8*)(Bl + swz256(16 * n + l15, k));
            acc[n] = MFMA16(af, bfr, acc[n]);
        }
    }

#pragma unroll
    for (int n = 0; n < 4; ++n) {
        int col = cb + 16 * n + l15;
        float bv = bias ? bias[col] : 0.f;
#pragma unroll
        for (int r = 0; r < 4; ++r) {
            int row = rb + 16 * w + l4 * 4 + r;
            Cb[(size_t)row * N + col] = (bf16_t)(acc[n][r] + bv);
        }
    }
}

// -------- seq gemm: C = A @ B^T + bias; writes C (bf16) AND C^T (bf16) -----
__global__ __launch_bounds__(256, 1)
void k_gemm_seqT(const bf16_t* __restrict__ A, const bf16_t* __restrict__ B,
                 const float* __restrict__ bias, bf16_t* __restrict__ Cb,
                 bf16_t* __restrict__ CTb) {
    __shared__ bf16_t Al[64 * 256];
    __shared__ bf16_t Bl[64 * 256];
    __shared__ float  Tt[64][65];
    const int tid  = threadIdx.x;
    const int lane = tid & 63;
    const int w    = tid >> 6;
    const int l15  = lane & 15;
    const int l4   = lane >> 4;
    const int rb = blockIdx.y * 64, cb = blockIdx.x * 64;

    {
        const u32x4* sa = (const u32x4*)(A + (size_t)rb * 256);
        const u32x4* sb = (const u32x4*)(B + (size_t)cb * 256);
        u32x4* da = (u32x4*)Al;
        u32x4* db = (u32x4*)Bl;
#pragma unroll
        for (int i = 0; i < 8; ++i) {
            int ch  = i * 256 + tid;
            int row = ch >> 5, cp = ch & 31;
            int sch = (ch & ~31) | (cp ^ (row & 7));
            da[sch] = sa[ch];
            db[sch] = sb[ch];
        }
    }
    __syncthreads();

    f32x4 acc[4];
#pragma unroll
    for (int n = 0; n < 4; ++n) acc[n] = (f32x4){0.f, 0.f, 0.f, 0.f};
#pragma unroll
    for (int t = 0; t < 8; ++t) {
        int k = t * 32 + l4 * 8;
        bf16x8 af = *(const bf16x8*)(Al + swz256(16 * w + l15, k));
#pragma unroll
        for (int n = 0; n < 4; ++n) {
            bf16x8 bfr = *(const bf16x8*)(Bl + swz256(16 * n + l15, k));
            acc[n] = MFMA16(af, bfr, acc[n]);
        }
    }

#pragma unroll
    for (int n = 0; n < 4; ++n) {
        int col = cb + 16 * n + l15;
        float bv = bias[col];
#pragma unroll
        for (int r = 0; r < 4; ++r) {
            int row = rb + 16 * w + l4 * 4 + r;
            float v = acc[n][r] + bv;
            Cb[(size_t)row * 256 + col] = (bf16_t)v;
            Tt[16 * n + l15][16 * w + l4 * 4 + r] = v;   // [local col][local row]
        }
    }
    __syncthreads();
#pragma unroll
    for (int i = 0; i < 16; ++i) {
        int e = i * 256 + tid;
        int lc = e >> 6, lr = e & 63;   // lc: local col (output row), lr: local row
        CTb[(size_t)(cb + lc) * 8192 + rb + lr] = (bf16_t)Tt[lc][lr];
    }
}

// ------------------------------- MHA (bf16 I/O) ----------------------------
__global__ __launch_bounds__(128, 1)
void k_mha(const bf16_t* __restrict__ qkv, bf16_t* __restrict__ attn) {
    __shared__ float Kl[128][17];
    __shared__ float Vl[128][17];
    const int bh = blockIdx.x;
    const int b = bh >> 4, h = bh & 15;
    const int t = threadIdx.x;
    const size_t rowbase = (size_t)b * 128;

    const bf16_t* base = qkv + (rowbase + t) * 768 + h * 16;
    bf16x8 qa = *(const bf16x8*)(base),       qb = *(const bf16x8*)(base + 8);
    bf16x8 ka = *(const bf16x8*)(base + 256), kb = *(const bf16x8*)(base + 264);
    bf16x8 va = *(const bf16x8*)(base + 512), vb = *(const bf16x8*)(base + 520);
    float q[16];
#pragma unroll
    for (int e = 0; e < 8; ++e) {
        q[e] = (float)qa[e]; q[8 + e] = (float)qb[e];
        Kl[t][e] = (float)ka[e]; Kl[t][8 + e] = (float)kb[e];
        Vl[t][e] = (float)va[e]; Vl[t][8 + e] = (float)vb[e];
    }
    __syncthreads();

    float m = -1e30f;
    for (int j = 0; j < 128; ++j) {
        float s = 0.f;
#pragma unroll
        for (int d = 0; d < 16; ++d) s += q[d] * Kl[j][d];
        m = fmaxf(m, s * 0.25f);
    }
    float sum = 0.f;
    float o[16];
#pragma unroll
    for (int d = 0; d < 16; ++d) o[d] = 0.f;
    for (int j = 0; j < 128; ++j) {
        float s = 0.f;
#pragma unroll
        for (int d = 0; d < 16; ++d) s += q[d] * Kl[j][d];
        float e = __expf(s * 0.25f - m);
        sum += e;
#pragma unroll
        for (int d = 0; d < 16; ++d) o[d] += e * Vl[j][d];
    }
    float inv = 1.f / sum;
    bf16_t* out = attn + (rowbase + t) * 256 + h * 16;
#pragma unroll
    for (int d = 0; d < 16; ++d) out[d] = (bf16_t)(o[d] * inv);
}

// ------------------- fused user-attention (the hot loop) -------------------
// BQ=128 q-rows per block, one j-half (4096 j, 64 iters of 64).
// S phase: 8 waves as 4(wr q-strip) x 2(wc j-half); U f32->bf16 frags in regs.
// PV phase: 8 waves REMAPPED as 2(pr q-half) x 4(pc d-quarter) to cut V-read
// redundancy. K/T tiles double-buffered, staged by global_load_lds DMA with
// pre-swizzled per-lane source addresses (LDS image = same swizzled layout).
__global__ __launch_bounds__(512, 2)
void k_user_attn(const float* __restrict__ Uf, const bf16_t* __restrict__ Sq,
                 const bf16_t* __restrict__ SqT, bf16_t* __restrict__ Opart,
                 float* __restrict__ rsp2) {
    __shared__ bf16_t Kl[2][64 * 256];   // seq tile  [64 j][256 d]  2x32 KB
    __shared__ bf16_t Tl[2][256 * 64];   // seqT tile [256 d][64 j]  2x32 KB
    __shared__ bf16_t Pl[128 * 64];      // scores    [128 q][64 j]  16 KB

    const int tid  = threadIdx.x;
    const int lane = tid & 63;
    const int wid  = tid >> 6;     // 0..7
    const int wr   = wid >> 1;     // S phase: 0..3, 32-row q strip
    const int wc   = wid & 1;      // S phase: 0..1, j half
    const int pr   = wid >> 2;     // PV phase: 0..1, 64-row q half
    const int pc   = wid & 3;      // PV phase: 0..3, 64-col d quarter
    const int l15  = lane & 15;
    const int l4   = lane >> 4;
    const int q0   = blockIdx.x * 128;
    const int jy   = blockIdx.y;   // 0..1
    const int jbase = jy * 4096;

    // ---- DMA source offsets (pre-swizzled; involution of the LDS swizzle) --
    int koff[4], toff[4];
#pragma unroll
    for (int i = 0; i < 4; ++i) {
        int c = wid * 256 + i * 64 + lane;            // dest chunk 0..2047
        int sc = (c & ~31) | ((c & 31) ^ ((c >> 5) & 7));
        koff[i] = sc * 16;                            // bytes into Sq tile
        int dr = c >> 3, scp = (c & 7) ^ (dr & 7);
        toff[i] = dr * 16384 + scp * 16;              // bytes into SqT (row=16KB)
    }
    auto stage_dma = [&](int b, int j0) {
        const char* gK = (const char*)Sq + (size_t)j0 * 512;
        const char* gT = (const char*)SqT + (size_t)j0 * 2;
        char* lK = (char*)(&Kl[b][0]) + wid * 4096;
        char* lT = (char*)(&Tl[b][0]) + wid * 4096;
#pragma unroll
        for (int i = 0; i < 4; ++i) {
            GLOAD_LDS16(gK + koff[i], lK + i * 1024);
            GLOAD_LDS16(gT + toff[i], lT + i * 1024);
        }
    };

    // ---- U fragments: load f32, convert to bf16 in regs ----
    bf16x8 uf[2][8];
#pragma unroll
    for (int rt = 0; rt < 2; ++rt) {
        const float* up = Uf + (size_t)(q0 + 32 * wr + 16 * rt + l15) * 256 + l4 * 8;
#pragma unroll
        for (int t = 0; t < 8; ++t) {
            float4 fa = *(const float4*)(up + t * 32);
            float4 fb = *(const float4*)(up + t * 32 + 4);
            bf16x8 v = { (bf16_t)fa.x, (bf16_t)fa.y, (bf16_t)fa.z, (bf16_t)fa.w,
                         (bf16_t)fb.x, (bf16_t)fb.y, (bf16_t)fb.z, (bf16_t)fb.w };
            uf[rt][t] = v;
        }
    }

    f32x4 oacc[2][4][2];   // [prt>>1? no: packed as [2][4] via loops below]
    // oacc[a][b][..] flattened: use [4][4] mapping prt x n
    f32x4 oa[4][4];
#pragma unroll
    for (int a = 0; a < 4; ++a)
#pragma unroll
        for (int b = 0; b < 4; ++b) oa[a][b] = (f32x4){0.f, 0.f, 0.f, 0.f};
    (void)oacc;
    float rsacc[2][4] = {{0.f, 0.f, 0.f, 0.f}, {0.f, 0.f, 0.f, 0.f}};

    // prologue: tile 0 -> buf0 via DMA, drain at barrier
    stage_dma(0, jbase);
    __syncthreads();

    char* Pb = (char*)Pl;
    for (int it = 0; it < 64; ++it) {
        const int cur = it & 1;
        const bf16_t* Klc = &Kl[cur][0];
        const bf16_t* Tlc = &Tl[cur][0];

        // issue next-tile DMA now; drained by the mid barrier (covered by S).
        if (it + 1 < 64) stage_dma(cur ^ 1, jbase + (it + 1) * 64);

        // ---- S phase: S[128x32(wc)] = U(regs) @ K_tile^T, K=256 ----
        f32x4 sacc[2][2];
#pragma unroll
        for (int rt = 0; rt < 2; ++rt)
#pragma unroll
            for (int jt = 0; jt < 2; ++jt) sacc[rt][jt] = (f32x4){0.f, 0.f, 0.f, 0.f};
#pragma unroll
        for (int t = 0; t < 8; ++t) {
            int k = t * 32 + l4 * 8;
#pragma unroll
            for (int jt = 0; jt < 2; ++jt) {
                bf16x8 bfr = *(const bf16x8*)(Klc + swz256(32 * wc + 16 * jt + l15, k));
#pragma unroll
                for (int rt = 0; rt < 2; ++rt)
                    sacc[rt][jt] = MFMA16(uf[rt][t], bfr, sacc[rt][jt]);
            }
        }
        // ---- |.| row partial sums + P -> bf16 LDS ----
#pragma unroll
        for (int rt = 0; rt < 2; ++rt)
#pragma unroll
            for (int jt = 0; jt < 2; ++jt)
#pragma unroll
                for (int r = 0; r < 4; ++r) {
                    float v = sacc[rt][jt][r];
                    rsacc[rt][r] += fabsf(v);
                    int prow = 32 * wr + 16 * rt + l4 * 4 + r;
                    int pcol = 32 * wc + 16 * jt + l15;
                    *(bf16_t*)(Pb + prow * 128 + ((pcol * 2) ^ pswz(prow))) = (bf16_t)v;
                }
        __syncthreads();   // P visible + next-tile DMA drained (vmcnt0)

        // ---- PV phase (remapped 2x4): O[64(pr) x 64(pc)] += P @ T^T, K=64 --
#pragma unroll
        for (int kt = 0; kt < 2; ++kt) {
            bf16x8 paf[4];
#pragma unroll
            for (int prt = 0; prt < 4; ++prt) {
                int prow = 64 * pr + 16 * prt + l15;
                paf[prt] = *(const bf16x8*)(Pb + prow * 128 + ((kt * 64 + l4 * 16) ^ pswz(prow)));
            }
#pragma unroll
            for (int n = 0; n < 4; ++n) {
                bf16x8 bfr = *(const bf16x8*)(Tlc + swz64(64 * pc + 16 * n + l15, kt * 32 + l4 * 8));
#pragma unroll
                for (int prt = 0; prt < 4; ++prt)
                    oa[prt][n] = MFMA16(paf[prt], bfr, oa[prt][n]);
            }
        }
        __syncthreads();   // PV reads done; next iter's DMA may overwrite
    }

    // ---- rowsum partials: 16-lane butterfly, write per-(jy,wc) slot ----
    float* rdst = rsp2 + (size_t)(jy * 2 + wc) * 16384 + q0;
#pragma unroll
    for (int rt = 0; rt < 2; ++rt)
#pragma unroll
        for (int r = 0; r < 4; ++r) {
            float v = rsacc[rt][r];
            v += __shfl_xor(v, 1, 16);
            v += __shfl_xor(v, 2, 16);
            v += __shfl_xor(v, 4, 16);
            v += __shfl_xor(v, 8, 16);
            if (l15 == 0) rdst[32 * wr + 16 * rt + 4 * l4 + r] = v;
        }

    bf16_t* ob = Opart + (size_t)jy * 16384 * 256;
#pragma unroll
    for (int prt = 0; prt < 4; ++prt)
#pragma unroll
        for (int r = 0; r < 4; ++r) {
            int row = q0 + 64 * pr + 16 * prt + l4 * 4 + r;
#pragma unroll
            for (int n = 0; n < 4; ++n)
                ob[(size_t)row * 256 + 64 * pc + 16 * n + l15] = (bf16_t)oa[prt][n][r];
        }
}

// ---- final: out = user + ((O0+O1)*inv) @ W^T + trans_b --------------------
__global__ __launch_bounds__(256, 1)
void k_final(const bf16_t* __restrict__ O, const float* __restrict__ rsp2,
             const bf16_t* __restrict__ W, const float* __restrict__ bias,
             const float* __restrict__ user, float* __restrict__ out) {
    __shared__ bf16_t Al[64 * 256];
    __shared__ bf16_t Bl[64 * 256];
    const int tid  = threadIdx.x;
    const int lane = tid & 63;
    const int w    = tid >> 6;
    const int l15  = lane & 15;
    const int l4   = lane >> 4;
    const int rb = blockIdx.y * 64, cb = blockIdx.x * 64;

    {   // A tile: combine O halves, p1-normalize, cvt bf16, swizzled store
        const bf16_t* O1 = O + (size_t)16384 * 256;
        u32x4* da = (u32x4*)Al;
        const u32x4* sb = (const u32x4*)(W + (size_t)cb * 256);
        u32x4* db = (u32x4*)Bl;
#pragma unroll
        for (int i = 0; i < 8; ++i) {
            int ch  = i * 256 + tid;
            int row = ch >> 5, cp = ch & 31;
            int grow = rb + row;
            float s = rsp2[grow] + rsp2[16384 + grow] + rsp2[32768 + grow] + rsp2[49152 + grow];
            float inv = 1.f / (fmaxf(s, 1e-12f) * 8192.f);
            bf16x8 a = *(const bf16x8*)(O  + (size_t)grow * 256 + cp * 8);
            bf16x8 b = *(const bf16x8*)(O1 + (size_t)grow * 256 + cp * 8);
            bf16x8 m;
#pragma unroll
            for (int e = 0; e < 8; ++e) m[e] = (bf16_t)(((float)a[e] + (float)b[e]) * inv);
            int sch = (ch & ~31) | (cp ^ (row & 7));
            *(bf16x8*)(Al + sch * 8) = m;
            db[sch] = sb[ch];
        }
    }
    __syncthreads();

    f32x4 acc[4];
#pragma unroll
    for (int n = 0; n < 4; ++n) acc[n] = (f32x4){0.f, 0.f, 0.f, 0.f};
#pragma unroll
    for (int t = 0; t < 8; ++t) {
        int k = t * 32 + l4 * 8;
        bf16x8 af = *(const bf16x8*)(Al + swz256(16 * w + l15, k));
#pragma unroll
        for (int n = 0; n < 4; ++n) {
            bf16x8 bfr = *(const bf16x8*)(Bl + swz256(16 * n + l15, k));
            acc[n] = MFMA16(af, bfr, acc[n]);
        }
    }
#pragma unroll
    for (int n = 0; n < 4; ++n) {
        int col = cb + 16 * n + l15;
        float bv = bias[col];
#pragma unroll
        for (int r = 0; r < 4; ++r) {
            int row = rb + 16 * w + l4 * 4 + r;
            size_t idx = (size_t)row * 256 + col;
            out[idx] = acc[n][r] + bv + user[idx];
        }
    }
}

// ---------------------------------------------------------------------------
extern "C" void kernel_launch(void* const* d_in, const int* in_sizes, int n_in,
                              void* d_out, int out_size, void* d_ws, size_t ws_size,
                              hipStream_t stream) {
    const float* user_feat  = (const float*)d_in[0];   // [16384,256]
    const float* seq_feat   = (const float*)d_in[1];   // [64,128,256]
    const float* in_proj_w  = (const float*)d_in[2];   // [768,256]
    const float* in_proj_b  = (const float*)d_in[3];   // [768]
    const float* out_proj_w = (const float*)d_in[4];   // [256,256]
    const float* out_proj_b = (const float*)d_in[5];   // [256]
    const float* trans_w    = (const float*)d_in[6];   // [256,256]
    const float* trans_b    = (const float*)d_in[7];   // [256]
    float* out = (float*)d_out;                        // [16384,256]

    char* w = (char*)d_ws;
    size_t off = 0;
    auto take = [&](size_t bytes) { void* p = w + off; off += (bytes + 255) & ~(size_t)255; return p; };
    bf16_t* Xb    = (bf16_t*)take((size_t)8192 * 256 * 2);   // dead after qkv gemm -> rsp2
    bf16_t* W1b   = (bf16_t*)take((size_t)768 * 256 * 2);
    bf16_t* W2b   = (bf16_t*)take((size_t)256 * 256 * 2);
    bf16_t* W3b   = (bf16_t*)take((size_t)256 * 256 * 2);
    bf16_t* attnb = (bf16_t*)take((size_t)8192 * 256 * 2);
    bf16_t* seqb  = (bf16_t*)take((size_t)8192 * 256 * 2);
    bf16_t* seqTb = (bf16_t*)take((size_t)256 * 8192 * 2);
    char*   regA  = (char*)take((size_t)8192 * 768 * 4);     // 25.17 MB shared region
    bf16_t* qkvb  = (bf16_t*)regA;                           // [8192,768] bf16, dies after MHA
    bf16_t* Opart = (bf16_t*)regA;                           // [2,16384,256] bf16 = 16.78 MB
    float*  rsp2  = (float*)Xb;                              // [4,16384] f32 (Xb dead by then)

    // 1) bf16 casts (seq_feat + weights; user stays f32)
    k_cvt<<<2048, 256, 0, stream>>>(seq_feat, Xb, 8192 * 256 / 4);
    k_cvt<<<192, 256, 0, stream>>>(in_proj_w, W1b, 768 * 256 / 4);
    k_cvt<<<64, 256, 0, stream>>>(out_proj_w, W2b, 256 * 256 / 4);
    k_cvt<<<64, 256, 0, stream>>>(trans_w, W3b, 256 * 256 / 4);

    // 2) qkv = seq_feat @ in_proj_w^T + in_proj_b   [8192,768] bf16
    k_gemm_bt<<<dim3(12, 128), 256, 0, stream>>>(Xb, W1b, in_proj_b, qkvb, 768);

    // 3) MHA -> attn bf16 [8192,256]
    k_mha<<<1024, 128, 0, stream>>>(qkvb, attnb);

    // 4) seq = attn @ out_proj_w^T + out_proj_b -> seqb + seqTb
    k_gemm_seqT<<<dim3(4, 128), 256, 0, stream>>>(attnb, W2b, out_proj_b, seqb, seqTb);

    // 5) fused user-attention, j-split x2 -> partials (DMA-staged)
    k_user_attn<<<dim3(128, 2), 512, 0, stream>>>(user_feat, seqb, seqTb, Opart, rsp2);

    // 6) out = user + combine(Opart)/(p1*M) @ trans_w^T + trans_b
    k_final<<<dim3(4, 256), 256, 0, stream>>>(Opart, rsp2, W3b, trans_b, user_feat, out);
}

// Round 5
// 183.704 us; speedup vs baseline: 1.4744x; 1.4744x over previous
//
#include <hip/hip_runtime.h>

// ---------------------------------------------------------------------------
// RefineIUGraphLayer: D=256, H=16, HD=16, N=16384, B=64, S=128, M=8192
// Key identity: p1-normalize only needs |.| in the DENOMINATOR.
//   att@S = (U Sᵀ) S = U (SᵀS) = U G          (exact, numerator is linear)
//   out   = user + diag(c) · U @ (G Wᵀ) + b,  c_i = 1/(max(r_i,1e-12)·M)
//   r_i   = Σ_j |u_i · s_j|                    (the only O(N·M·D) kernel left)
// Pipeline:
//   1) qkv  = seq_feat @ in_proj_wᵀ + b        (bf16 MFMA gemm)
//   2) attn = MHA(qkv)                         (f32 per-thread)
//   3) seq  = attn @ out_proj_wᵀ + b           (gemm, writes seq + seqᵀ)
//   4) r    = rowabs(U @ seqᵀ)                 (hot: abs-reduce GEMM)
//   5) G    = seqᵀ seq (split-K partials)      (tiny)
//   6) Hᵀ   = (ΣGpart) @ trans_wᵀ  (transposed out, bf16)
//   7) out  = user + diag(c)·(U@H) + trans_b   (final gemm)
// ---------------------------------------------------------------------------

typedef __bf16 bf16_t;
typedef __bf16 bf16x8 __attribute__((ext_vector_type(8)));
typedef __bf16 bf16x4 __attribute__((ext_vector_type(4)));
typedef float  f32x4  __attribute__((ext_vector_type(4)));
typedef unsigned int u32x4 __attribute__((ext_vector_type(4)));

#define MFMA16(a, b, c) __builtin_amdgcn_mfma_f32_16x16x32_bf16((a), (b), (c), 0, 0, 0)

#define AS1 __attribute__((address_space(1)))
#define AS3 __attribute__((address_space(3)))
#define GLOAD_LDS16(g, l) \
    __builtin_amdgcn_global_load_lds((const AS1 unsigned int*)(const void*)(g), \
                                     (AS3 unsigned int*)(void*)(l), 16, 0, 0)

// 3-bit chunk XOR swizzle (involution; same on write & read).
__device__ __forceinline__ int swz256(int row, int k) { return row * 256 + (k ^ ((row & 7) << 3)); }

// --------------------------- f32 -> bf16 convert ---------------------------
__global__ void k_cvt(const float* __restrict__ s, bf16_t* __restrict__ d, int n4) {
    int i  = blockIdx.x * blockDim.x + threadIdx.x;
    int st = gridDim.x * blockDim.x;
    for (; i < n4; i += st) {
        float4 v = ((const float4*)s)[i];
        bf16x4 o = { (bf16_t)v.x, (bf16_t)v.y, (bf16_t)v.z, (bf16_t)v.w };
        ((bf16x4*)d)[i] = o;
    }
}

// --------------- generic C = A @ Bᵀ + bias, bf16 out -----------------------
__global__ __launch_bounds__(256, 1)
void k_gemm_bt(const bf16_t* __restrict__ A, const bf16_t* __restrict__ B,
               const float* __restrict__ bias, bf16_t* __restrict__ Cb, int N) {
    __shared__ bf16_t Al[64 * 256];
    __shared__ bf16_t Bl[64 * 256];
    const int tid  = threadIdx.x;
    const int lane = tid & 63;
    const int w    = tid >> 6;
    const int l15  = lane & 15;
    const int l4   = lane >> 4;
    const int rb = blockIdx.y * 64, cb = blockIdx.x * 64;

    {
        const u32x4* sa = (const u32x4*)(A + (size_t)rb * 256);
        const u32x4* sb = (const u32x4*)(B + (size_t)cb * 256);
        u32x4* da = (u32x4*)Al;
        u32x4* db = (u32x4*)Bl;
#pragma unroll
        for (int i = 0; i < 8; ++i) {
            int ch  = i * 256 + tid;
            int row = ch >> 5, cp = ch & 31;
            int sch = (ch & ~31) | (cp ^ (row & 7));
            da[sch] = sa[ch];
            db[sch] = sb[ch];
        }
    }
    __syncthreads();

    f32x4 acc[4];
#pragma unroll
    for (int n = 0; n < 4; ++n) acc[n] = (f32x4){0.f, 0.f, 0.f, 0.f};
#pragma unroll
    for (int t = 0; t < 8; ++t) {
        int k = t * 32 + l4 * 8;
        bf16x8 af = *(const bf16x8*)(Al + swz256(16 * w + l15, k));
#pragma unroll
        for (int n = 0; n < 4; ++n) {
            bf16x8 bfr = *(const bf16x8*)(Bl + swz256(16 * n + l15, k));
            acc[n] = MFMA16(af, bfr, acc[n]);
        }
    }
#pragma unroll
    for (int n = 0; n < 4; ++n) {
        int col = cb + 16 * n + l15;
        float bv = bias ? bias[col] : 0.f;
#pragma unroll
        for (int r = 0; r < 4; ++r) {
            int row = rb + 16 * w + l4 * 4 + r;
            Cb[(size_t)row * N + col] = (bf16_t)(acc[n][r] + bv);
        }
    }
}

// -------- seq gemm: C = A @ Bᵀ + bias; writes C (bf16) AND Cᵀ (bf16) -------
__global__ __launch_bounds__(256, 1)
void k_gemm_seqT(const bf16_t* __restrict__ A, const bf16_t* __restrict__ B,
                 const float* __restrict__ bias, bf16_t* __restrict__ Cb,
                 bf16_t* __restrict__ CTb) {
    __shared__ bf16_t Al[64 * 256];
    __shared__ bf16_t Bl[64 * 256];
    __shared__ float  Tt[64][65];
    const int tid  = threadIdx.x;
    const int lane = tid & 63;
    const int w    = tid >> 6;
    const int l15  = lane & 15;
    const int l4   = lane >> 4;
    const int rb = blockIdx.y * 64, cb = blockIdx.x * 64;

    {
        const u32x4* sa = (const u32x4*)(A + (size_t)rb * 256);
        const u32x4* sb = (const u32x4*)(B + (size_t)cb * 256);
        u32x4* da = (u32x4*)Al;
        u32x4* db = (u32x4*)Bl;
#pragma unroll
        for (int i = 0; i < 8; ++i) {
            int ch  = i * 256 + tid;
            int row = ch >> 5, cp = ch & 31;
            int sch = (ch & ~31) | (cp ^ (row & 7));
            da[sch] = sa[ch];
            db[sch] = sb[ch];
        }
    }
    __syncthreads();

    f32x4 acc[4];
#pragma unroll
    for (int n = 0; n < 4; ++n) acc[n] = (f32x4){0.f, 0.f, 0.f, 0.f};
#pragma unroll
    for (int t = 0; t < 8; ++t) {
        int k = t * 32 + l4 * 8;
        bf16x8 af = *(const bf16x8*)(Al + swz256(16 * w + l15, k));
#pragma unroll
        for (int n = 0; n < 4; ++n) {
            bf16x8 bfr = *(const bf16x8*)(Bl + swz256(16 * n + l15, k));
            acc[n] = MFMA16(af, bfr, acc[n]);
        }
    }
#pragma unroll
    for (int n = 0; n < 4; ++n) {
        int col = cb + 16 * n + l15;
        float bv = bias[col];
#pragma unroll
        for (int r = 0; r < 4; ++r) {
            int row = rb + 16 * w + l4 * 4 + r;
            float v = acc[n][r] + bv;
            Cb[(size_t)row * 256 + col] = (bf16_t)v;
            Tt[16 * n + l15][16 * w + l4 * 4 + r] = v;
        }
    }
    __syncthreads();
#pragma unroll
    for (int i = 0; i < 16; ++i) {
        int e = i * 256 + tid;
        int lc = e >> 6, lr = e & 63;
        CTb[(size_t)(cb + lc) * 8192 + rb + lr] = (bf16_t)Tt[lc][lr];
    }
}

// ------------------------------- MHA (bf16 I/O) ----------------------------
__global__ __launch_bounds__(128, 1)
void k_mha(const bf16_t* __restrict__ qkv, bf16_t* __restrict__ attn) {
    __shared__ float Kl[128][17];
    __shared__ float Vl[128][17];
    const int bh = blockIdx.x;
    const int b = bh >> 4, h = bh & 15;
    const int t = threadIdx.x;
    const size_t rowbase = (size_t)b * 128;

    const bf16_t* base = qkv + (rowbase + t) * 768 + h * 16;
    bf16x8 qa = *(const bf16x8*)(base),       qb = *(const bf16x8*)(base + 8);
    bf16x8 ka = *(const bf16x8*)(base + 256), kb = *(const bf16x8*)(base + 264);
    bf16x8 va = *(const bf16x8*)(base + 512), vb = *(const bf16x8*)(base + 520);
    float q[16];
#pragma unroll
    for (int e = 0; e < 8; ++e) {
        q[e] = (float)qa[e]; q[8 + e] = (float)qb[e];
        Kl[t][e] = (float)ka[e]; Kl[t][8 + e] = (float)kb[e];
        Vl[t][e] = (float)va[e]; Vl[t][8 + e] = (float)vb[e];
    }
    __syncthreads();

    float m = -1e30f;
    for (int j = 0; j < 128; ++j) {
        float s = 0.f;
#pragma unroll
        for (int d = 0; d < 16; ++d) s += q[d] * Kl[j][d];
        m = fmaxf(m, s * 0.25f);
    }
    float sum = 0.f;
    float o[16];
#pragma unroll
    for (int d = 0; d < 16; ++d) o[d] = 0.f;
    for (int j = 0; j < 128; ++j) {
        float s = 0.f;
#pragma unroll
        for (int d = 0; d < 16; ++d) s += q[d] * Kl[j][d];
        float e = __expf(s * 0.25f - m);
        sum += e;
#pragma unroll
        for (int d = 0; d < 16; ++d) o[d] += e * Vl[j][d];
    }
    float inv = 1.f / sum;
    bf16_t* out = attn + (rowbase + t) * 256 + h * 16;
#pragma unroll
    for (int d = 0; d < 16; ++d) out[d] = (bf16_t)(o[d] * inv);
}

// ------------------- k_rowabs: r_i = sum_j |u_i . s_j| (hot) ---------------
// BQ=128, BK=64, j-split x2. 8 waves = 2(wr: 64-q strip) x 4(wc: 16-j strip).
// U fragments register-resident (128 VGPR); K-tile double-buffered via
// global_load_lds DMA (pre-swizzled source). ONE barrier per iter.
__global__ __launch_bounds__(512, 2)
void k_rowabs(const bf16_t* __restrict__ Ub, const bf16_t* __restrict__ Sq,
              float* __restrict__ rsp) {
    __shared__ bf16_t Kl[2][64 * 256];   // 2 x 32 KB

    const int tid  = threadIdx.x;
    const int lane = tid & 63;
    const int wid  = tid >> 6;     // 0..7
    const int wr   = wid >> 2;     // 0..1 : 64-row q strip
    const int wc   = wid & 3;      // 0..3 : 16-col j strip
    const int l15  = lane & 15;
    const int l4   = lane >> 4;
    const int q0   = blockIdx.x * 128;
    const int jy   = blockIdx.y;
    const int jbase = jy * 4096;

    // DMA source offsets: dest chunk c -> pre-swizzled source chunk
    int koff[4];
#pragma unroll
    for (int i = 0; i < 4; ++i) {
        int c = wid * 256 + i * 64 + lane;
        int sc = (c & ~31) | ((c & 31) ^ ((c >> 5) & 7));
        koff[i] = sc * 16;
    }
    auto stage = [&](int b, int j0) {
        const char* gK = (const char*)Sq + (size_t)j0 * 512;
        char* lK = (char*)(&Kl[b][0]) + wid * 4096;
#pragma unroll
        for (int i = 0; i < 4; ++i) GLOAD_LDS16(gK + koff[i], lK + i * 1024);
    };

    // U fragments: rows q0 + 64*wr + 16*rt + l15
    bf16x8 uf[4][8];
#pragma unroll
    for (int rt = 0; rt < 4; ++rt) {
        const bf16_t* up = Ub + (size_t)(q0 + 64 * wr + 16 * rt + l15) * 256 + l4 * 8;
#pragma unroll
        for (int t = 0; t < 8; ++t) uf[rt][t] = *(const bf16x8*)(up + t * 32);
    }

    float rsacc[4][4];
#pragma unroll
    for (int rt = 0; rt < 4; ++rt)
#pragma unroll
        for (int r = 0; r < 4; ++r) rsacc[rt][r] = 0.f;

    stage(0, jbase);
    __syncthreads();

    for (int it = 0; it < 64; ++it) {
        const int cur = it & 1;
        if (it + 1 < 64) stage(cur ^ 1, jbase + (it + 1) * 64);
        const bf16_t* Klc = &Kl[cur][0];

        f32x4 sacc[4];
#pragma unroll
        for (int rt = 0; rt < 4; ++rt) sacc[rt] = (f32x4){0.f, 0.f, 0.f, 0.f};
#pragma unroll
        for (int t = 0; t < 8; ++t) {
            int k = t * 32 + l4 * 8;
            bf16x8 bfr = *(const bf16x8*)(Klc + swz256(16 * wc + l15, k));
#pragma unroll
            for (int rt = 0; rt < 4; ++rt)
                sacc[rt] = MFMA16(uf[rt][t], bfr, sacc[rt]);
        }
#pragma unroll
        for (int rt = 0; rt < 4; ++rt)
#pragma unroll
            for (int r = 0; r < 4; ++r) rsacc[rt][r] += fabsf(sacc[rt][r]);
        __syncthreads();   // reads of cur done; DMA to cur^1 drained (vmcnt0)
    }

    // reduce over j within strip (16 lanes), write per-(jy,wc) partial
    float* rdst = rsp + (size_t)(jy * 4 + wc) * 16384 + q0 + 64 * wr;
#pragma unroll
    for (int rt = 0; rt < 4; ++rt)
#pragma unroll
        for (int r = 0; r < 4; ++r) {
            float v = rsacc[rt][r];
            v += __shfl_xor(v, 1, 16);
            v += __shfl_xor(v, 2, 16);
            v += __shfl_xor(v, 4, 16);
            v += __shfl_xor(v, 8, 16);
            if (l15 == 0) rdst[16 * rt + 4 * l4 + r] = v;
        }
}

// ---- rs[i] = 1/(max(sum_p rsp[p][i],1e-12)*8192) --------------------------
__global__ void k_rs(const float* __restrict__ rsp, float* __restrict__ rs) {
    int i = blockIdx.x * blockDim.x + threadIdx.x;
    float s = 0.f;
#pragma unroll
    for (int p = 0; p < 8; ++p) s += rsp[(size_t)p * 16384 + i];
    rs[i] = 1.f / (fmaxf(s, 1e-12f) * 8192.f);
}

// ---- Gpart[kz] = ST[rb:,:1024 slice] @ STᵀ (64x64 tile, f32) --------------
__global__ __launch_bounds__(256, 1)
void k_gram(const bf16_t* __restrict__ ST, float* __restrict__ Gpart) {
    __shared__ bf16_t Al[64 * 256];
    __shared__ bf16_t Bl[64 * 256];
    const int tid = threadIdx.x, lane = tid & 63, w = tid >> 6;
    const int l15 = lane & 15, l4 = lane >> 4;
    const int rb = blockIdx.y * 64, cb = blockIdx.x * 64;
    const int jb = blockIdx.z * 1024;

    f32x4 acc[4];
#pragma unroll
    for (int n = 0; n < 4; ++n) acc[n] = (f32x4){0.f, 0.f, 0.f, 0.f};

    for (int kt4 = 0; kt4 < 4; ++kt4) {
        int j0 = jb + kt4 * 256;
        __syncthreads();
        u32x4* da = (u32x4*)Al;
        u32x4* db = (u32x4*)Bl;
#pragma unroll
        for (int i = 0; i < 8; ++i) {
            int ch  = i * 256 + tid;
            int row = ch >> 5, cp = ch & 31;
            int sch = (ch & ~31) | (cp ^ (row & 7));
            da[sch] = *(const u32x4*)(ST + (size_t)(rb + row) * 8192 + j0 + cp * 8);
            db[sch] = *(const u32x4*)(ST + (size_t)(cb + row) * 8192 + j0 + cp * 8);
        }
        __syncthreads();
#pragma unroll
        for (int t = 0; t < 8; ++t) {
            int k = t * 32 + l4 * 8;
            bf16x8 af = *(const bf16x8*)(Al + swz256(16 * w + l15, k));
#pragma unroll
            for (int n = 0; n < 4; ++n) {
                bf16x8 bfr = *(const bf16x8*)(Bl + swz256(16 * n + l15, k));
                acc[n] = MFMA16(af, bfr, acc[n]);
            }
        }
    }
    float* gp = Gpart + (size_t)blockIdx.z * 65536;
#pragma unroll
    for (int n = 0; n < 4; ++n)
#pragma unroll
        for (int r = 0; r < 4; ++r)
            gp[(size_t)(rb + 16 * w + l4 * 4 + r) * 256 + cb + 16 * n + l15] = acc[n][r];
}

// ---- HT = ((sum Gpart) @ trans_wᵀ) transposed, bf16 -----------------------
__global__ __launch_bounds__(256, 1)
void k_gh(const float* __restrict__ Gpart, const float* __restrict__ W,
          bf16_t* __restrict__ HT) {
    __shared__ bf16_t Al[64 * 256];
    __shared__ bf16_t Bl[64 * 256];
    const int tid = threadIdx.x, lane = tid & 63, w = tid >> 6;
    const int l15 = lane & 15, l4 = lane >> 4;
    const int rb = blockIdx.y * 64, cb = blockIdx.x * 64;

#pragma unroll
    for (int i = 0; i < 16; ++i) {
        int idx = i * 1024 + tid * 4;          // 4-aligned element in 64x256
        int row = idx >> 8, col = idx & 255;
        f32x4 s = *(const f32x4*)(Gpart + (size_t)(rb + row) * 256 + col);
#pragma unroll
        for (int p = 1; p < 8; ++p)
            s += *(const f32x4*)(Gpart + (size_t)p * 65536 + (size_t)(rb + row) * 256 + col);
        f32x4 wv = *(const f32x4*)(W + (size_t)(cb + row) * 256 + col);
        int sc = col ^ ((row & 7) << 3);
        bf16x4 ga = { (bf16_t)s[0], (bf16_t)s[1], (bf16_t)s[2], (bf16_t)s[3] };
        bf16x4 wb = { (bf16_t)wv[0], (bf16_t)wv[1], (bf16_t)wv[2], (bf16_t)wv[3] };
        *(bf16x4*)(Al + row * 256 + sc) = ga;
        *(bf16x4*)(Bl + row * 256 + sc) = wb;
    }
    __syncthreads();

    f32x4 acc[4];
#pragma unroll
    for (int n = 0; n < 4; ++n) acc[n] = (f32x4){0.f, 0.f, 0.f, 0.f};
#pragma unroll
    for (int t = 0; t < 8; ++t) {
        int k = t * 32 + l4 * 8;
        bf16x8 af = *(const bf16x8*)(Al + swz256(16 * w + l15, k));
#pragma unroll
        for (int n = 0; n < 4; ++n) {
            bf16x8 bfr = *(const bf16x8*)(Bl + swz256(16 * n + l15, k));
            acc[n] = MFMA16(af, bfr, acc[n]);
        }
    }
#pragma unroll
    for (int n = 0; n < 4; ++n)
#pragma unroll
        for (int r = 0; r < 4; ++r)
            HT[(size_t)(cb + 16 * n + l15) * 256 + rb + 16 * w + l4 * 4 + r] =
                (bf16_t)acc[n][r];
}

// ---- final: out = user + diag(rs) * (U @ HTᵀ) + trans_b -------------------
__global__ __launch_bounds__(256, 1)
void k_final(const bf16_t* __restrict__ A, const bf16_t* __restrict__ B,
             const float* __restrict__ rs, const float* __restrict__ tb,
             const float* __restrict__ user, float* __restrict__ out) {
    __shared__ bf16_t Al[64 * 256];
    __shared__ bf16_t Bl[64 * 256];
    const int tid  = threadIdx.x;
    const int lane = tid & 63;
    const int w    = tid >> 6;
    const int l15  = lane & 15;
    const int l4   = lane >> 4;
    const int rb = blockIdx.y * 64, cb = blockIdx.x * 64;

    {
        const u32x4* sa = (const u32x4*)(A + (size_t)rb * 256);
        const u32x4* sb = (const u32x4*)(B + (size_t)cb * 256);
        u32x4* da = (u32x4*)Al;
        u32x4* db = (u32x4*)Bl;
#pragma unroll
        for (int i = 0; i < 8; ++i) {
            int ch  = i * 256 + tid;
            int row = ch >> 5, cp = ch & 31;
            int sch = (ch & ~31) | (cp ^ (row & 7));
            da[sch] = sa[ch];
            db[sch] = sb[ch];
        }
    }
    __syncthreads();

    f32x4 acc[4];
#pragma unroll
    for (int n = 0; n < 4; ++n) acc[n] = (f32x4){0.f, 0.f, 0.f, 0.f};
#pragma unroll
    for (int t = 0; t < 8; ++t) {
        int k = t * 32 + l4 * 8;
        bf16x8 af = *(const bf16x8*)(Al + swz256(16 * w + l15, k));
#pragma unroll
        for (int n = 0; n < 4; ++n) {
            bf16x8 bfr = *(const bf16x8*)(Bl + swz256(16 * n + l15, k));
            acc[n] = MFMA16(af, bfr, acc[n]);
        }
    }
    float c[4];
#pragma unroll
    for (int r = 0; r < 4; ++r) c[r] = rs[rb + 16 * w + l4 * 4 + r];
#pragma unroll
    for (int n = 0; n < 4; ++n) {
        int col = cb + 16 * n + l15;
        float bv = tb[col];
#pragma unroll
        for (int r = 0; r < 4; ++r) {
            int row = rb + 16 * w + l4 * 4 + r;
            size_t idx = (size_t)row * 256 + col;
            out[idx] = user[idx] + c[r] * acc[n][r] + bv;
        }
    }
}

// ---------------------------------------------------------------------------
extern "C" void kernel_launch(void* const* d_in, const int* in_sizes, int n_in,
                              void* d_out, int out_size, void* d_ws, size_t ws_size,
                              hipStream_t stream) {
    const float* user_feat  = (const float*)d_in[0];   // [16384,256]
    const float* seq_feat   = (const float*)d_in[1];   // [64,128,256]
    const float* in_proj_w  = (const float*)d_in[2];   // [768,256]
    const float* in_proj_b  = (const float*)d_in[3];   // [768]
    const float* out_proj_w = (const float*)d_in[4];   // [256,256]
    const float* out_proj_b = (const float*)d_in[5];   // [256]
    const float* trans_w    = (const float*)d_in[6];   // [256,256]
    const float* trans_b    = (const float*)d_in[7];   // [256]
    float* out = (float*)d_out;                        // [16384,256]

    char* w = (char*)d_ws;
    size_t off = 0;
    auto take = [&](size_t bytes) { void* p = w + off; off += (bytes + 255) & ~(size_t)255; return p; };
    bf16_t* Ub    = (bf16_t*)take((size_t)16384 * 256 * 2);
    bf16_t* Xb    = (bf16_t*)take((size_t)8192 * 256 * 2);   // dead after qkv -> rsp/rs
    bf16_t* W1b   = (bf16_t*)take((size_t)768 * 256 * 2);
    bf16_t* W2b   = (bf16_t*)take((size_t)256 * 256 * 2);
    bf16_t* attnb = (bf16_t*)take((size_t)8192 * 256 * 2);
    bf16_t* seqb  = (bf16_t*)take((size_t)8192 * 256 * 2);
    bf16_t* seqTb = (bf16_t*)take((size_t)256 * 8192 * 2);
    char*   regA  = (char*)take((size_t)8192 * 768 * 4);     // 25.17 MB shared region
    bf16_t* qkvb  = (bf16_t*)regA;                           // [8192,768] bf16, dies after MHA
    float*  Gpart = (float*)regA;                            // [8,256,256] f32 = 2 MB
    bf16_t* HTb   = (bf16_t*)(regA + (size_t)8 * 65536 * 4); // [256,256] bf16
    float*  rsp   = (float*)Xb;                              // [8,16384] f32
    float*  rs    = (float*)(Xb + (size_t)8 * 16384 * 2);    // [16384] f32 (after rsp)

    // 1) bf16 casts
    k_cvt<<<2048, 256, 0, stream>>>(user_feat, Ub, 16384 * 256 / 4);
    k_cvt<<<2048, 256, 0, stream>>>(seq_feat, Xb, 8192 * 256 / 4);
    k_cvt<<<192, 256, 0, stream>>>(in_proj_w, W1b, 768 * 256 / 4);
    k_cvt<<<64, 256, 0, stream>>>(out_proj_w, W2b, 256 * 256 / 4);

    // 2) qkv = seq_feat @ in_proj_wᵀ + in_proj_b   [8192,768] bf16
    k_gemm_bt<<<dim3(12, 128), 256, 0, stream>>>(Xb, W1b, in_proj_b, qkvb, 768);

    // 3) MHA -> attn bf16 [8192,256]
    k_mha<<<1024, 128, 0, stream>>>(qkvb, attnb);

    // 4) seq = attn @ out_proj_wᵀ + out_proj_b -> seqb + seqTb
    k_gemm_seqT<<<dim3(4, 128), 256, 0, stream>>>(attnb, W2b, out_proj_b, seqb, seqTb);

    // 5) rowabs partials (hot)
    k_rowabs<<<dim3(128, 2), 512, 0, stream>>>(Ub, seqb, rsp);
    k_rs<<<64, 256, 0, stream>>>(rsp, rs);

    // 6) G partials, then HT = (G @ trans_wᵀ)ᵀ bf16
    k_gram<<<dim3(4, 4, 8), 256, 0, stream>>>(seqTb, Gpart);
    k_gh<<<dim3(4, 4), 256, 0, stream>>>(Gpart, trans_w, HTb);

    // 7) out = user + diag(rs)·(U@H) + trans_b
    k_final<<<dim3(4, 256), 256, 0, stream>>>(Ub, HTb, rs, trans_b, user_feat, out);
}